// Round 9
// baseline (3436.861 us; speedup 1.0000x reference)
//
#include <hip/hip_runtime.h>

#define TS    256
#define ROWS  16
#define DIN   28
#define RING  8

typedef _Float16 f16x4 __attribute__((ext_vector_type(4)));
typedef float    f32x4 __attribute__((ext_vector_type(4)));

#if __has_builtin(__builtin_amdgcn_rcpf)
#define RCPF(x) __builtin_amdgcn_rcpf(x)
#else
#define RCPF(x) (1.0f / (x))
#endif
#if __has_builtin(__builtin_amdgcn_exp2f)
#define EXP2F(x) __builtin_amdgcn_exp2f(x)
#else
#define EXP2F(x) exp2f(x)
#endif

// ===== FROZEN gate math (R2/R3/R7 proven) =====
__device__ __forceinline__ float sigm(float x) {
  return RCPF(1.0f + EXP2F(x * -1.44269504f));
}
__device__ __forceinline__ float tanhf_(float x) {
  return 1.0f - 2.0f * RCPF(1.0f + EXP2F(x * 2.885390082f));
}
__device__ __forceinline__ f16x4 cvt4(float a, float b, float c, float d) {
  f16x4 r; r[0] = (_Float16)a; r[1] = (_Float16)b; r[2] = (_Float16)c; r[3] = (_Float16)d;
  return r;
}
__device__ __forceinline__ f16x4 cvt4v(float4 v) { return cvt4(v.x, v.y, v.z, v.w); }

#define MFMA16(a, b, c) __builtin_amdgcn_mfma_f32_16x16x16f16((a), (b), (c), 0, 0, 0)

#define LDA_AGENT(p) __hip_atomic_load((p), __ATOMIC_ACQUIRE, __HIP_MEMORY_SCOPE_AGENT)
#define STR_AGENT(p, v) __hip_atomic_store((p), (v), __ATOMIC_RELEASE, __HIP_MEMORY_SCOPE_AGENT)
#define LDX_AGENT(p) __hip_atomic_load((p), __ATOMIC_RELAXED, __HIP_MEMORY_SCOPE_AGENT)
#define STX_AGENT(p, v) __hip_atomic_store((p), (v), __ATOMIC_RELAXED, __HIP_MEMORY_SCOPE_AGENT)

// ============================================================================
// Pair kernel: grid 512 x 512thr. Blocks [0,256) = layers 0-1 ("A"), blocks
// [256,512) = layers 2-3 ("B") for the same 16 rows (pair p shares an XCD:
// 256 % 8 == 0). Each block: R2-proven internal barrier diagonal (2 layers x
// 4 col-waves). h^1 -> layer 2 crosses blocks via a ring-8 buffer in d_ws:
// data = relaxed-agent u64 (sc1, coherent path), flags = single monotonic
// int per pair per direction (acquire/release agent). Co-residency is
// guaranteed: launch_bounds(512,4) caps regs at 128 -> 4 waves/SIMD -> 2
// blocks/CU -> all 512 blocks resident; (l,t) wait DAG is acyclic.
// Ring timing: A exports h^1_t at phase t+2 (coalesced from LDS by waves 0-1),
// publishes pflag=t at phase t+3 (barrier drained stores). B at phase t reads
// slot t&7 after pflag>=t; publishes cflag=t at phase t+1. A polls
// cflag >= s-9 before overwriting (slot tenant age 8). Lag in [3,8] phases.
// ============================================================================
__global__ __launch_bounds__(512, 4) void lstm4_pair(
    const float* __restrict__ x,
    const float* __restrict__ Wih0, const float* __restrict__ Whh0,
    const float* __restrict__ bih0, const float* __restrict__ bhh0,
    const float* __restrict__ Wih1, const float* __restrict__ Whh1,
    const float* __restrict__ bih1, const float* __restrict__ bhh1,
    const float* __restrict__ Wih2, const float* __restrict__ Whh2,
    const float* __restrict__ bih2, const float* __restrict__ bhh2,
    const float* __restrict__ Wih3, const float* __restrict__ Whh3,
    const float* __restrict__ bih3, const float* __restrict__ bhh3,
    const float* __restrict__ Wout, const float* __restrict__ bout,
    float* __restrict__ out,
    _Float16* __restrict__ gbuf, int* __restrict__ pflag, int* __restrict__ cflag)
{
  const int tid  = (int)threadIdx.x;
  const int lane = tid & 63;
  const int w    = tid >> 6;    // 0..7
  const int lw   = w >> 2;      // local layer 0,1
  const int wv   = w & 3;       // col tile
  const int r    = lane & 15;
  const int q    = lane >> 4;
  const int bid  = (int)blockIdx.x;
  const int roleB = bid >> 8;   // 0: layers 0-1, 1: layers 2-3
  const int p    = bid & 255;
  const int r0   = p * ROWS;

  __shared__ _Float16 hb[2][2][ROWS][72] __attribute__((aligned(16)));
  for (int i = tid; i < 2 * 2 * ROWS * 72; i += 512)
    (&hb[0][0][0][0])[i] = (_Float16)0.0f;
  __syncthreads();

  const int l = roleB * 2 + lw;  // global layer of this wave
  const float* Wih = (l == 0) ? Wih0 : (l == 1) ? Wih1 : (l == 2) ? Wih2 : Wih3;
  const float* Whh = (l == 0) ? Whh0 : (l == 1) ? Whh1 : (l == 2) ? Whh2 : Whh3;
  const float* bih = (l == 0) ? bih0 : (l == 1) ? bih1 : (l == 2) ? bih2 : bih3;
  const float* bhh = (l == 0) ? bhh0 : (l == 1) ? bhh1 : (l == 2) ? bhh2 : bhh3;

  // R2-proven fragment packing (x16 MFMA, f16x4, k = 16s+4q+i)
  f16x4 wx[4][4];
  f16x4 wh[4][4];
  float bv[4];
#pragma unroll
  for (int nt = 0; nt < 4; ++nt) {
    const int col = 64 * nt + 16 * wv + r;
    if (l == 0) {
      wx[nt][0] = cvt4v(*(const float4*)&Wih[col * DIN + 4 * q]);
      wx[nt][1] = (q < 3) ? cvt4v(*(const float4*)&Wih[col * DIN + 16 + 4 * q])
                          : cvt4(0.f, 0.f, 0.f, 0.f);
      wx[nt][2] = cvt4(0.f, 0.f, 0.f, 0.f);
      wx[nt][3] = cvt4(0.f, 0.f, 0.f, 0.f);
    } else {
#pragma unroll
      for (int s = 0; s < 4; ++s)
        wx[nt][s] = cvt4v(*(const float4*)&Wih[col * 64 + 16 * s + 4 * q]);
    }
#pragma unroll
    for (int s = 0; s < 4; ++s)
      wh[nt][s] = cvt4v(*(const float4*)&Whh[col * 64 + 16 * s + 4 * q]);
    bv[nt] = bih[col] + bhh[col];
  }

  // layer-0 x pipeline
  const float* xrow = x + (size_t)(r0 + r) * (TS * DIN);
  f16x4 xa0 = cvt4(0.f, 0.f, 0.f, 0.f), xa1 = xa0;
  if (l == 0) {
    xa0 = cvt4v(*(const float4*)&xrow[4 * q]);
    if (q < 3) xa1 = cvt4v(*(const float4*)&xrow[16 + 4 * q]);
  }

  f32x4 cst = f32x4{0.f, 0.f, 0.f, 0.f};
  _Float16* gslab = gbuf + (size_t)p * (RING * ROWS * 64);

  const int SMAX = roleB ? 256 : 258;
  for (int s = 0; s <= SMAX; ++s) {
    if (tid == 0) {  // pairwise gating by one thread, then barrier holds all
      if (!roleB) {
        const int tgt = s - 9;  // overwrite guard for ring tenant
        int it = 0;
        while (LDA_AGENT(&cflag[p]) < tgt && ++it < (1 << 24))
          __builtin_amdgcn_s_sleep(2);
      } else if (s < 256) {
        int it = 0;
        while (LDA_AGENT(&pflag[p]) < s && ++it < (1 << 24))
          __builtin_amdgcn_s_sleep(2);
      }
    }
    __syncthreads();

    const int t = s - lw;
    if (t >= 0 && t < TS) {
      const int sl = t & 1, sp = sl ^ 1;

      f32x4 acc[4];
#pragma unroll
      for (int nt = 0; nt < 4; ++nt)
        acc[nt] = f32x4{bv[nt], bv[nt], bv[nt], bv[nt]};

      if (l == 0) {
#pragma unroll
        for (int nt = 0; nt < 4; ++nt) acc[nt] = MFMA16(xa0, wx[nt][0], acc[nt]);
#pragma unroll
        for (int nt = 0; nt < 4; ++nt) acc[nt] = MFMA16(xa1, wx[nt][1], acc[nt]);
        if (t + 1 < TS) {
          const float* xp = &xrow[(t + 1) * DIN + 4 * q];
          const float4 v0 = *(const float4*)xp;
          float4 v1 = make_float4(0.f, 0.f, 0.f, 0.f);
          if (q < 3) v1 = *(const float4*)&xrow[(t + 1) * DIN + 16 + 4 * q];
          xa0 = cvt4v(v0);
          xa1 = cvt4v(v1);
        }
      } else if (l == 2) {
        // input h^1_t from the cross-block ring (relaxed-agent u64, coherent)
        const unsigned long long* gs =
            (const unsigned long long*)(gslab + (size_t)(t & 7) * (ROWS * 64) + r * 64);
#pragma unroll
        for (int s2 = 0; s2 < 4; ++s2) {
          const unsigned long long v = LDX_AGENT(&gs[(16 * s2 + 4 * q) >> 2]);
          const f16x4 a = __builtin_bit_cast(f16x4, v);
#pragma unroll
          for (int nt = 0; nt < 4; ++nt) acc[nt] = MFMA16(a, wx[nt][s2], acc[nt]);
        }
      } else {
        // l==1 or l==3: input h^{l-1}_t from local LDS (written last phase)
#pragma unroll
        for (int s2 = 0; s2 < 4; ++s2) {
          const f16x4 a = *(const f16x4*)&hb[0][sl][r][16 * s2 + 4 * q];
#pragma unroll
          for (int nt = 0; nt < 4; ++nt) acc[nt] = MFMA16(a, wx[nt][s2], acc[nt]);
        }
      }
      {  // recurrence h^l_{t-1} from own LDS ring
#pragma unroll
        for (int s2 = 0; s2 < 4; ++s2) {
          const f16x4 a = *(const f16x4*)&hb[lw][sp][r][16 * s2 + 4 * q];
#pragma unroll
          for (int nt = 0; nt < 4; ++nt) acc[nt] = MFMA16(a, wh[nt][s2], acc[nt]);
        }
      }

      // frozen elementwise gate block; scatter h to own LDS slot
      _Float16* pw = &hb[lw][sl][4 * q][16 * wv + r];
#pragma unroll
      for (int j = 0; j < 4; ++j) {
        const float ig = sigm(acc[0][j]);
        const float fg = sigm(acc[1][j]);
        const float gg = tanhf_(acc[2][j]);
        const float og = sigm(acc[3][j]);
        const float c  = fg * cst[j] + ig * gg;
        cst[j] = c;
        pw[j * 72] = (_Float16)(og * tanhf_(c));
      }
    }

    // A-block export duty (waves 0-1): coalesced LDS->global of h^1_{s-2}
    if (!roleB && w < 2) {
      const int te = s - 2;
      if (te >= 0 && te < TS) {
        const int e   = (w << 6) | lane;   // 0..127 -> 16B granule
        const int row = e >> 3, c16 = e & 7;
        const unsigned long long* src =
            (const unsigned long long*)&hb[1][te & 1][row][c16 * 8];
        unsigned long long* dst = (unsigned long long*)(
            gslab + (size_t)(te & 7) * (ROWS * 64) + row * 64 + c16 * 8);
        STX_AGENT(&dst[0], src[0]);
        STX_AGENT(&dst[1], src[1]);
      }
    }

    if (tid == 0) {
      if (!roleB) {
        // h^1_{s-3} exported in phase s-1; drained at this phase's barrier
        if (s >= 3) STR_AGENT(&pflag[p], s - 3);
      } else {
        if (s >= 1) STR_AGENT(&cflag[p], s - 1);  // consumed t = s-1
      }
    }
  }

  __syncthreads();

  // epilogue (B blocks): h^3_255 in hb[1][1]; final linear [16 x 10]
  if (roleB && tid < 160) {
    const int rr = tid & 15;
    const int oc = tid >> 4;
    float a = bout[oc];
#pragma unroll 16
    for (int k = 0; k < 64; ++k)
      a += (float)hb[1][1][rr][k] * Wout[oc * 64 + k];
    out[(size_t)(r0 + rr) * 10 + oc] = a;
  }
}

// ============================================================================
// Fallback: R2's proven kernel (506 us) if ws_size is too small for the ring.
// ============================================================================
__global__ __launch_bounds__(1024, 4) void lstm4_pipe(
    const float* __restrict__ x,
    const float* __restrict__ Wih0, const float* __restrict__ Whh0,
    const float* __restrict__ bih0, const float* __restrict__ bhh0,
    const float* __restrict__ Wih1, const float* __restrict__ Whh1,
    const float* __restrict__ bih1, const float* __restrict__ bhh1,
    const float* __restrict__ Wih2, const float* __restrict__ Whh2,
    const float* __restrict__ bih2, const float* __restrict__ bhh2,
    const float* __restrict__ Wih3, const float* __restrict__ Whh3,
    const float* __restrict__ bih3, const float* __restrict__ bhh3,
    const float* __restrict__ Wout, const float* __restrict__ bout,
    float* __restrict__ out)
{
  const int tid  = (int)threadIdx.x;
  const int lane = tid & 63;
  const int w    = tid >> 6;
  const int l    = w >> 2;
  const int wv   = w & 3;
  const int r    = lane & 15;
  const int q    = lane >> 4;
  const int r0   = (int)blockIdx.x * ROWS;

  __shared__ _Float16 hbuf[4][2][ROWS][72];
  for (int i = tid; i < 4 * 2 * ROWS * 72; i += 1024)
    (&hbuf[0][0][0][0])[i] = (_Float16)0.0f;

  const float* Wih = (l == 0) ? Wih0 : (l == 1) ? Wih1 : (l == 2) ? Wih2 : Wih3;
  const float* Whh = (l == 0) ? Whh0 : (l == 1) ? Whh1 : (l == 2) ? Whh2 : Whh3;
  const float* bih = (l == 0) ? bih0 : (l == 1) ? bih1 : (l == 2) ? bih2 : bih3;
  const float* bhh = (l == 0) ? bhh0 : (l == 1) ? bhh1 : (l == 2) ? bhh2 : bhh3;

  f16x4 wx[4][4];
  f16x4 wh[4][4];
  float bv[4];
#pragma unroll
  for (int nt = 0; nt < 4; ++nt) {
    const int col = 64 * nt + 16 * wv + r;
    if (l == 0) {
      wx[nt][0] = cvt4v(*(const float4*)&Wih[col * DIN + 4 * q]);
      wx[nt][1] = (q < 3) ? cvt4v(*(const float4*)&Wih[col * DIN + 16 + 4 * q])
                          : cvt4(0.f, 0.f, 0.f, 0.f);
      wx[nt][2] = cvt4(0.f, 0.f, 0.f, 0.f);
      wx[nt][3] = cvt4(0.f, 0.f, 0.f, 0.f);
    } else {
#pragma unroll
      for (int s = 0; s < 4; ++s)
        wx[nt][s] = cvt4v(*(const float4*)&Wih[col * 64 + 16 * s + 4 * q]);
    }
#pragma unroll
    for (int s = 0; s < 4; ++s)
      wh[nt][s] = cvt4v(*(const float4*)&Whh[col * 64 + 16 * s + 4 * q]);
    bv[nt] = bih[col] + bhh[col];
  }

  const float* xrow = x + (size_t)(r0 + r) * (TS * DIN);
  f16x4 xa0 = cvt4(0.f, 0.f, 0.f, 0.f), xa1 = xa0;
  if (l == 0) {
    xa0 = cvt4v(*(const float4*)&xrow[4 * q]);
    if (q < 3) xa1 = cvt4v(*(const float4*)&xrow[16 + 4 * q]);
  }

  f32x4 cst = f32x4{0.f, 0.f, 0.f, 0.f};

  for (int s = 0; s < TS + 3; ++s) {
    __syncthreads();
    const int t = s - l;
    if (t < 0 || t >= TS) continue;
    const int pi = t & 1;

    f32x4 acc[4];
#pragma unroll
    for (int nt = 0; nt < 4; ++nt)
      acc[nt] = f32x4{bv[nt], bv[nt], bv[nt], bv[nt]};

    if (l == 0) {
#pragma unroll
      for (int nt = 0; nt < 4; ++nt) acc[nt] = MFMA16(xa0, wx[nt][0], acc[nt]);
#pragma unroll
      for (int nt = 0; nt < 4; ++nt) acc[nt] = MFMA16(xa1, wx[nt][1], acc[nt]);
      if (t + 1 < TS) {
        const float4 v0 = *(const float4*)&xrow[(t + 1) * DIN + 4 * q];
        float4 v1 = make_float4(0.f, 0.f, 0.f, 0.f);
        if (q < 3) v1 = *(const float4*)&xrow[(t + 1) * DIN + 16 + 4 * q];
        xa0 = cvt4v(v0);
        xa1 = cvt4v(v1);
      }
    } else {
      const _Float16* pin = &hbuf[l - 1][pi][r][4 * q];
#pragma unroll
      for (int s2 = 0; s2 < 4; ++s2) {
        const f16x4 a = *(const f16x4*)&pin[16 * s2];
#pragma unroll
        for (int nt = 0; nt < 4; ++nt) acc[nt] = MFMA16(a, wx[nt][s2], acc[nt]);
      }
    }
    {
      const _Float16* prc = &hbuf[l][pi ^ 1][r][4 * q];
#pragma unroll
      for (int s2 = 0; s2 < 4; ++s2) {
        const f16x4 a = *(const f16x4*)&prc[16 * s2];
#pragma unroll
        for (int nt = 0; nt < 4; ++nt) acc[nt] = MFMA16(a, wh[nt][s2], acc[nt]);
      }
    }

    _Float16* pw = &hbuf[l][pi][4 * q][16 * wv + r];
#pragma unroll
    for (int j = 0; j < 4; ++j) {
      const float ig = sigm(acc[0][j]);
      const float fg = sigm(acc[1][j]);
      const float gg = tanhf_(acc[2][j]);
      const float og = sigm(acc[3][j]);
      const float c  = fg * cst[j] + ig * gg;
      cst[j] = c;
      pw[j * 72] = (_Float16)(og * tanhf_(c));
    }
  }

  __syncthreads();
  if (tid < 160) {
    const int rr = tid & 15;
    const int oc = tid >> 4;
    float a = bout[oc];
#pragma unroll 16
    for (int k = 0; k < 64; ++k)
      a += (float)hbuf[3][1][rr][k] * Wout[oc * 64 + k];
    out[(size_t)(r0 + rr) * 10 + oc] = a;
  }
}

extern "C" void kernel_launch(void* const* d_in, const int* in_sizes, int n_in,
                              void* d_out, int out_size, void* d_ws, size_t ws_size,
                              hipStream_t stream) {
  (void)in_sizes; (void)n_in; (void)out_size;
  const size_t GBYTES = (size_t)256 * RING * ROWS * 64 * sizeof(_Float16);  // 4 MiB
  const size_t NEED   = GBYTES + 4096;

  if (ws_size < NEED) {  // proven fallback
    lstm4_pipe<<<dim3(4096 / ROWS), dim3(1024), 0, stream>>>(
        (const float*)d_in[0],
        (const float*)d_in[1],  (const float*)d_in[2],  (const float*)d_in[3],  (const float*)d_in[4],
        (const float*)d_in[5],  (const float*)d_in[6],  (const float*)d_in[7],  (const float*)d_in[8],
        (const float*)d_in[9],  (const float*)d_in[10], (const float*)d_in[11], (const float*)d_in[12],
        (const float*)d_in[13], (const float*)d_in[14], (const float*)d_in[15], (const float*)d_in[16],
        (const float*)d_in[17], (const float*)d_in[18],
        (float*)d_out);
    return;
  }

  _Float16* gbuf = (_Float16*)d_ws;
  int* pflag = (int*)((char*)d_ws + GBYTES);   // [256]
  int* cflag = pflag + 256;                    // [256]
  // flags := -1 every launch (deterministic; graph-capture safe)
  hipMemsetAsync(pflag, 0xFF, 2 * 256 * sizeof(int), stream);

  lstm4_pair<<<dim3(512), dim3(512), 0, stream>>>(
      (const float*)d_in[0],
      (const float*)d_in[1],  (const float*)d_in[2],  (const float*)d_in[3],  (const float*)d_in[4],
      (const float*)d_in[5],  (const float*)d_in[6],  (const float*)d_in[7],  (const float*)d_in[8],
      (const float*)d_in[9],  (const float*)d_in[10], (const float*)d_in[11], (const float*)d_in[12],
      (const float*)d_in[13], (const float*)d_in[14], (const float*)d_in[15], (const float*)d_in[16],
      (const float*)d_in[17], (const float*)d_in[18],
      (float*)d_out, gbuf, pflag, cflag);
}

// Round 10
// 987.922 us; speedup vs baseline: 3.4789x; 3.4789x over previous
//
#include <hip/hip_runtime.h>

#define TS    256
#define ROWS  16
#define DIN   28

typedef _Float16 f16x4 __attribute__((ext_vector_type(4)));
typedef float    f32x4 __attribute__((ext_vector_type(4)));

#if __has_builtin(__builtin_amdgcn_rcpf)
#define RCPF(x) __builtin_amdgcn_rcpf(x)
#else
#define RCPF(x) (1.0f / (x))
#endif
#if __has_builtin(__builtin_amdgcn_exp2f)
#define EXP2F(x) __builtin_amdgcn_exp2f(x)
#else
#define EXP2F(x) exp2f(x)
#endif

// ===== FROZEN gate math (R2/R3/R7 proven) =====
__device__ __forceinline__ float sigm(float x) {
  return RCPF(1.0f + EXP2F(x * -1.44269504f));
}
__device__ __forceinline__ float tanhf_(float x) {
  return 1.0f - 2.0f * RCPF(1.0f + EXP2F(x * 2.885390082f));
}
__device__ __forceinline__ f16x4 cvt4(float a, float b, float c, float d) {
  f16x4 r; r[0] = (_Float16)a; r[1] = (_Float16)b; r[2] = (_Float16)c; r[3] = (_Float16)d;
  return r;
}
__device__ __forceinline__ f16x4 cvt4v(float4 v) { return cvt4(v.x, v.y, v.z, v.w); }

#define MFMA16(a, b, c) __builtin_amdgcn_mfma_f32_16x16x16f16((a), (b), (c), 0, 0, 0)

#define ST_REL(p, v) __hip_atomic_store((p), (v), __ATOMIC_RELEASE, __HIP_MEMORY_SCOPE_WORKGROUP)

__device__ __forceinline__ int imin(int a, int b) { return a < b ? a : b; }

// R3-proven spin: volatile reads + s_sleep; caller fences before touching data
__device__ __forceinline__ void wait4(volatile const int* f, int T) {
  int a = f[0], b = f[1], c = f[2], d = f[3];
  while (imin(imin(a, b), imin(c, d)) < T) {
    __builtin_amdgcn_s_sleep(1);
    a = f[0]; b = f[1]; c = f[2]; d = f[3];
  }
}

// R2 skeleton (16 waves = 4 layers x 4 col-waves, barrier diagonal) with TWO
// timesteps per barrier phase: 131 barriers instead of 259, amortizing the
// ~1900 cyc/phase convoy. h lives in a ring-4 LDS buffer (slot = t&3): all
// cross-layer reads / overwrites stay barrier-separated (audited). The only
// intra-phase edge -- step B's recurrence needs the group's own 4-wave h_T --
// uses one LDS-flag microsync per phase (R3-proven spin+fence primitives;
// waves are in lockstep from the same barrier, so expected spin ~ 0).
__global__ __launch_bounds__(1024, 4) void lstm4_p2(
    const float* __restrict__ x,
    const float* __restrict__ Wih0, const float* __restrict__ Whh0,
    const float* __restrict__ bih0, const float* __restrict__ bhh0,
    const float* __restrict__ Wih1, const float* __restrict__ Whh1,
    const float* __restrict__ bih1, const float* __restrict__ bhh1,
    const float* __restrict__ Wih2, const float* __restrict__ Whh2,
    const float* __restrict__ bih2, const float* __restrict__ bhh2,
    const float* __restrict__ Wih3, const float* __restrict__ Whh3,
    const float* __restrict__ bih3, const float* __restrict__ bhh3,
    const float* __restrict__ Wout, const float* __restrict__ bout,
    float* __restrict__ out)
{
  const int tid  = (int)threadIdx.x;
  const int lane = tid & 63;
  const int w    = tid >> 6;   // wave 0..15
  const int l    = w >> 2;     // layer 0..3
  const int wv   = w & 3;      // col tile -> h cols [16wv,16wv+16)
  const int r    = lane & 15;  // batch row
  const int q    = lane >> 4;  // quarter group
  const int r0   = (int)blockIdx.x * ROWS;

  __shared__ _Float16 hbuf[4][4][ROWS][72] __attribute__((aligned(16)));  // [layer][t&3][row][col]
  __shared__ int mflag[4][4];  // [layer][wv]: last phase whose step-A h-write is done

  for (int i = tid; i < 4 * 4 * ROWS * 72; i += 1024)
    (&hbuf[0][0][0][0])[i] = (_Float16)0.0f;
  if (tid < 16) (&mflag[0][0])[tid] = -1;
  __syncthreads();

  const float* Wih = (l == 0) ? Wih0 : (l == 1) ? Wih1 : (l == 2) ? Wih2 : Wih3;
  const float* Whh = (l == 0) ? Whh0 : (l == 1) ? Whh1 : (l == 2) ? Whh2 : Whh3;
  const float* bih = (l == 0) ? bih0 : (l == 1) ? bih1 : (l == 2) ? bih2 : bih3;
  const float* bhh = (l == 0) ? bhh0 : (l == 1) ? bhh1 : (l == 2) ? bhh2 : bhh3;

  // R2-proven fragment packing (x16 MFMA, k = 16s+4q+i)
  f16x4 wx[4][4];
  f16x4 wh[4][4];
  float bv[4];
#pragma unroll
  for (int nt = 0; nt < 4; ++nt) {
    const int col = 64 * nt + 16 * wv + r;
    if (l == 0) {
      wx[nt][0] = cvt4v(*(const float4*)&Wih[col * DIN + 4 * q]);
      wx[nt][1] = (q < 3) ? cvt4v(*(const float4*)&Wih[col * DIN + 16 + 4 * q])
                          : cvt4(0.f, 0.f, 0.f, 0.f);
      wx[nt][2] = cvt4(0.f, 0.f, 0.f, 0.f);
      wx[nt][3] = cvt4(0.f, 0.f, 0.f, 0.f);
    } else {
#pragma unroll
      for (int s = 0; s < 4; ++s)
        wx[nt][s] = cvt4v(*(const float4*)&Wih[col * 64 + 16 * s + 4 * q]);
    }
#pragma unroll
    for (int s = 0; s < 4; ++s)
      wh[nt][s] = cvt4v(*(const float4*)&Whh[col * 64 + 16 * s + 4 * q]);
    bv[nt] = bih[col] + bhh[col];
  }

  // layer-0 x pipeline: both timesteps of the CURRENT phase held as raw float4
  const float* xrow = x + (size_t)(r0 + r) * (TS * DIN);
  float4 pxa0 = make_float4(0.f, 0.f, 0.f, 0.f), pxa1 = pxa0, pxb0 = pxa0, pxb1 = pxa0;
  if (l == 0) {
    pxa0 = *(const float4*)&xrow[4 * q];
    if (q < 3) pxa1 = *(const float4*)&xrow[16 + 4 * q];
    pxb0 = *(const float4*)&xrow[DIN + 4 * q];
    if (q < 3) pxb1 = *(const float4*)&xrow[DIN + 16 + 4 * q];
  }

  f32x4 cst = f32x4{0.f, 0.f, 0.f, 0.f};

  for (int P = 0; P < TS / 2 + 3; ++P) {   // 131 phases
    __syncthreads();
    const int T = 2 * (P - l);
    if (T < 0 || T >= TS) continue;        // wave-uniform; whole group skips together

    // convert this phase's x fragments before the prefetch overwrites them
    f16x4 xaA0{}, xaA1{}, xaB0{}, xaB1{};
    if (l == 0) {
      xaA0 = cvt4v(pxa0); xaA1 = cvt4v(pxa1);
      xaB0 = cvt4v(pxb0); xaB1 = cvt4v(pxb1);
    }

    const int sA = T & 3;
    const int sR = (T - 1) & 3;  // T=0 -> slot 3 (zero-initialized)
    const int sB = (T + 1) & 3;

    // ================= step A: t = T =================
    {
      f32x4 acc[4];
#pragma unroll
      for (int nt = 0; nt < 4; ++nt)
        acc[nt] = f32x4{bv[nt], bv[nt], bv[nt], bv[nt]};

      if (l == 0) {
#pragma unroll
        for (int nt = 0; nt < 4; ++nt) acc[nt] = MFMA16(xaA0, wx[nt][0], acc[nt]);
#pragma unroll
        for (int nt = 0; nt < 4; ++nt) acc[nt] = MFMA16(xaA1, wx[nt][1], acc[nt]);
      } else {
        const _Float16* pin = &hbuf[l - 1][sA][r][4 * q];
#pragma unroll
        for (int s2 = 0; s2 < 4; ++s2) {
          const f16x4 a = *(const f16x4*)&pin[16 * s2];
#pragma unroll
          for (int nt = 0; nt < 4; ++nt) acc[nt] = MFMA16(a, wx[nt][s2], acc[nt]);
        }
      }
      {
        const _Float16* prc = &hbuf[l][sR][r][4 * q];
#pragma unroll
        for (int s2 = 0; s2 < 4; ++s2) {
          const f16x4 a = *(const f16x4*)&prc[16 * s2];
#pragma unroll
          for (int nt = 0; nt < 4; ++nt) acc[nt] = MFMA16(a, wh[nt][s2], acc[nt]);
        }
      }

      _Float16* pw = &hbuf[l][sA][4 * q][16 * wv + r];
#pragma unroll
      for (int j = 0; j < 4; ++j) {
        const float ig = sigm(acc[0][j]);
        const float fg = sigm(acc[1][j]);
        const float gg = tanhf_(acc[2][j]);
        const float og = sigm(acc[3][j]);
        const float c  = fg * cst[j] + ig * gg;
        cst[j] = c;
        pw[j * 72] = (_Float16)(og * tanhf_(c));
      }
    }

    // prefetch next phase's x now (global latency hides under microsync+step B)
    if (l == 0 && T + 2 < TS) {
      const float* xp = &xrow[(T + 2) * DIN];
      pxa0 = *(const float4*)&xp[4 * q];
      pxa1 = (q < 3) ? *(const float4*)&xp[16 + 4 * q] : make_float4(0.f, 0.f, 0.f, 0.f);
      pxb0 = *(const float4*)&xp[DIN + 4 * q];
      pxb1 = (q < 3) ? *(const float4*)&xp[DIN + 16 + 4 * q] : make_float4(0.f, 0.f, 0.f, 0.f);
    }

    // ============ intra-group microsync (R3-proven primitives) ============
    __threadfence_block();                    // drain our step-A h-writes
    if (lane == 0) ST_REL(&mflag[l][wv], P);
    wait4(&mflag[l][0], P);                   // all 4 col-waves done step A
    __threadfence_block();                    // acquire before reading h_T

    // ================= step B: t = T+1 =================
    {
      f32x4 acc[4];
#pragma unroll
      for (int nt = 0; nt < 4; ++nt)
        acc[nt] = f32x4{bv[nt], bv[nt], bv[nt], bv[nt]};

      if (l == 0) {
#pragma unroll
        for (int nt = 0; nt < 4; ++nt) acc[nt] = MFMA16(xaB0, wx[nt][0], acc[nt]);
#pragma unroll
        for (int nt = 0; nt < 4; ++nt) acc[nt] = MFMA16(xaB1, wx[nt][1], acc[nt]);
      } else {
        const _Float16* pin = &hbuf[l - 1][sB][r][4 * q];
#pragma unroll
        for (int s2 = 0; s2 < 4; ++s2) {
          const f16x4 a = *(const f16x4*)&pin[16 * s2];
#pragma unroll
          for (int nt = 0; nt < 4; ++nt) acc[nt] = MFMA16(a, wx[nt][s2], acc[nt]);
        }
      }
      {
        const _Float16* prc = &hbuf[l][sA][r][4 * q];  // h_T, just synced
#pragma unroll
        for (int s2 = 0; s2 < 4; ++s2) {
          const f16x4 a = *(const f16x4*)&prc[16 * s2];
#pragma unroll
          for (int nt = 0; nt < 4; ++nt) acc[nt] = MFMA16(a, wh[nt][s2], acc[nt]);
        }
      }

      _Float16* pw = &hbuf[l][sB][4 * q][16 * wv + r];
#pragma unroll
      for (int j = 0; j < 4; ++j) {
        const float ig = sigm(acc[0][j]);
        const float fg = sigm(acc[1][j]);
        const float gg = tanhf_(acc[2][j]);
        const float og = sigm(acc[3][j]);
        const float c  = fg * cst[j] + ig * gg;
        cst[j] = c;
        pw[j * 72] = (_Float16)(og * tanhf_(c));
      }
    }
  }

  __syncthreads();

  // h3_255 is in slot 255 & 3 = 3; final linear [16 rows] x [10 out]
  if (tid < 160) {
    const int rr = tid & 15;
    const int oc = tid >> 4;
    float a = bout[oc];
#pragma unroll 16
    for (int k = 0; k < 64; ++k)
      a += (float)hbuf[3][3][rr][k] * Wout[oc * 64 + k];
    out[(size_t)(r0 + rr) * 10 + oc] = a;
  }
}

extern "C" void kernel_launch(void* const* d_in, const int* in_sizes, int n_in,
                              void* d_out, int out_size, void* d_ws, size_t ws_size,
                              hipStream_t stream) {
  (void)in_sizes; (void)n_in; (void)d_ws; (void)ws_size; (void)out_size;
  lstm4_p2<<<dim3(4096 / ROWS), dim3(1024), 0, stream>>>(
      (const float*)d_in[0],
      (const float*)d_in[1],  (const float*)d_in[2],  (const float*)d_in[3],  (const float*)d_in[4],
      (const float*)d_in[5],  (const float*)d_in[6],  (const float*)d_in[7],  (const float*)d_in[8],
      (const float*)d_in[9],  (const float*)d_in[10], (const float*)d_in[11], (const float*)d_in[12],
      (const float*)d_in[13], (const float*)d_in[14], (const float*)d_in[15], (const float*)d_in[16],
      (const float*)d_in[17], (const float*)d_in[18],
      (float*)d_out);
}